// Round 3
// baseline (1891.069 us; speedup 1.0000x reference)
//
#include <hip/hip_runtime.h>

#define NN 20000
#define NE 160000

typedef __bf16 bf16x8 __attribute__((ext_vector_type(8)));
typedef float f32x4 __attribute__((ext_vector_type(4)));

union U16B { uint4 v; unsigned short s[8]; };

__device__ __forceinline__ float b2f(unsigned short u) {
  return __uint_as_float(((unsigned int)u) << 16);
}
__device__ __forceinline__ unsigned short f2b(float f) {
  unsigned int x = __float_as_uint(f);
  x += 0x7fffu + ((x >> 16) & 1u);
  return (unsigned short)(x >> 16);
}
__device__ __forceinline__ float gelu_f(float v) {
  return 0.5f * v * (1.f + erff(v * 0.70710678118654752f));
}
__device__ __forceinline__ float lrelu(float v) { return v > 0.f ? v : 0.2f * v; }

// ---------------- input dtype detection ----------------
// Views first 4096 u16 of W1 as bf16. fp32 buffer -> odd halves are random
// mantissa bits -> ~40% extreme exponents. bf16 buffer (N(0,0.044)) -> ~none.
__global__ void detect_k(const unsigned short* __restrict__ w, int* __restrict__ flag) {
  __shared__ int bad;
  if (threadIdx.x == 0) bad = 0;
  __syncthreads();
  int cnt = 0;
  for (int i = threadIdx.x; i < 4096; i += 256) {
    unsigned int e = (w[i] >> 7) & 0xFFu;
    if (e < 100u || e > 154u) cnt++;
  }
  atomicAdd(&bad, cnt);
  __syncthreads();
  if (threadIdx.x == 0) *flag = (bad > 200) ? 1 : 0;   // 1 = inputs are fp32
}

// Normalize an input tensor to bf16 workspace copy.
__global__ void conv_k(const void* __restrict__ src, unsigned short* __restrict__ dst,
                       int n, const int* __restrict__ flag) {
  int i = blockIdx.x * blockDim.x + threadIdx.x;
  if (i >= n) return;
  if (*flag) dst[i] = f2b(((const float*)src)[i]);
  else       dst[i] = ((const unsigned short*)src)[i];
}

// ---------------- CSR build (dst-sorted) ----------------
__global__ void hist_k(const int* __restrict__ dst, int* __restrict__ deg) {
  int e = blockIdx.x * blockDim.x + threadIdx.x;
  if (e < NE) atomicAdd(&deg[dst[e]], 1);
}

__global__ __launch_bounds__(1024) void scan_k(const int* __restrict__ deg,
                                               int* __restrict__ indptr,
                                               int* __restrict__ cursor) {
  __shared__ int buf[1024];
  __shared__ int carryS;
  int tid = threadIdx.x;
  if (tid == 0) { carryS = 0; indptr[0] = 0; }
  __syncthreads();
  for (int base = 0; base < NN; base += 1024) {
    int i = base + tid;
    int v = (i < NN) ? deg[i] : 0;
    buf[tid] = v;
    __syncthreads();
    for (int off = 1; off < 1024; off <<= 1) {
      int t = (tid >= off) ? buf[tid - off] : 0;
      __syncthreads();
      buf[tid] += t;
      __syncthreads();
    }
    int c = carryS;
    if (i < NN) {
      indptr[i + 1] = c + buf[tid];
      cursor[i] = c + buf[tid] - v;   // exclusive
    }
    __syncthreads();
    if (tid == 0) carryS = c + buf[1023];
    __syncthreads();
  }
}

__global__ void scatter_k(const int* __restrict__ dst, int* __restrict__ cursor,
                          int* __restrict__ eidx) {
  int e = blockIdx.x * blockDim.x + threadIdx.x;
  if (e < NE) {
    int p = atomicAdd(&cursor[dst[e]], 1);
    eidx[p] = e;
  }
}

// ---------------- bf16 MFMA GEMM ----------------
__global__ __launch_bounds__(256) void gemm_k(const unsigned short* __restrict__ A,
                                              const unsigned short* __restrict__ W,
                                              unsigned short* __restrict__ C,
                                              int M, int K, int ldW, int ldC) {
  __shared__ unsigned short As[64][40];
  __shared__ unsigned short Bs[64][40];
  int tid = threadIdx.x;
  int wave = tid >> 6, lane = tid & 63;
  int wm = wave >> 1, wn = wave & 1;
  int quad = lane >> 4, l16 = lane & 15;
  int m0 = blockIdx.x * 64, n0 = blockIdx.y * 64;

  f32x4 acc[2][2];
#pragma unroll
  for (int mi = 0; mi < 2; mi++)
#pragma unroll
    for (int ni = 0; ni < 2; ni++) acc[mi][ni] = (f32x4){0.f, 0.f, 0.f, 0.f};

  int arow = tid >> 2, acol = (tid & 3) << 3;
  int brow = tid >> 3, bcol = (tid & 7) << 3;

  for (int k0 = 0; k0 < K; k0 += 32) {
    uint4 av = make_uint4(0u, 0u, 0u, 0u);
    int gr = m0 + arow;
    if (gr < M) av = *(const uint4*)(A + (size_t)gr * K + k0 + acol);
    *(uint4*)(&As[arow][acol]) = av;
    uint4 bv = *(const uint4*)(W + (size_t)(k0 + brow) * ldW + n0 + bcol);
    U16B u; u.v = bv;
#pragma unroll
    for (int j = 0; j < 8; j++) Bs[bcol + j][brow] = u.s[j];
    __syncthreads();
    bf16x8 af0 = *(bf16x8*)(&As[wm * 32 + l16][quad * 8]);
    bf16x8 af1 = *(bf16x8*)(&As[wm * 32 + 16 + l16][quad * 8]);
    bf16x8 bg0 = *(bf16x8*)(&Bs[wn * 32 + l16][quad * 8]);
    bf16x8 bg1 = *(bf16x8*)(&Bs[wn * 32 + 16 + l16][quad * 8]);
    acc[0][0] = __builtin_amdgcn_mfma_f32_16x16x32_bf16(af0, bg0, acc[0][0], 0, 0, 0);
    acc[0][1] = __builtin_amdgcn_mfma_f32_16x16x32_bf16(af0, bg1, acc[0][1], 0, 0, 0);
    acc[1][0] = __builtin_amdgcn_mfma_f32_16x16x32_bf16(af1, bg0, acc[1][0], 0, 0, 0);
    acc[1][1] = __builtin_amdgcn_mfma_f32_16x16x32_bf16(af1, bg1, acc[1][1], 0, 0, 0);
    __syncthreads();
  }
#pragma unroll
  for (int mi = 0; mi < 2; mi++)
#pragma unroll
    for (int ni = 0; ni < 2; ni++) {
      int row0 = m0 + wm * 32 + mi * 16 + quad * 4;
      int col = n0 + wn * 32 + ni * 16 + l16;
#pragma unroll
      for (int r = 0; r < 4; r++) {
        int row = row0 + r;
        if (row < M) C[(size_t)row * ldC + col] = f2b(acc[mi][ni][r]);
      }
    }
}

// ---------------- attention logits for group of 2 heads ----------------
__global__ __launch_bounds__(128) void elr_k(const unsigned short* __restrict__ feat,
                                             const unsigned short* __restrict__ al,
                                             const unsigned short* __restrict__ ar,
                                             float* __restrict__ el, float* __restrict__ er,
                                             int F, int GF) {
  int n = blockIdx.x;
  int wave = threadIdx.x >> 6, lane = threadIdx.x & 63;
  const unsigned short* fp = feat + (size_t)n * GF + wave * F;
  const unsigned short* alp = al + wave * F;
  const unsigned short* arp = ar + wave * F;
  float sl = 0.f, sr = 0.f;
  for (int f = lane; f < F; f += 64) {
    float fv = b2f(fp[f]);
    sl += fv * b2f(alp[f]);
    sr += fv * b2f(arp[f]);
  }
#pragma unroll
  for (int off = 32; off > 0; off >>= 1) {
    sl += __shfl_down(sl, off);
    sr += __shfl_down(sr, off);
  }
  if (lane == 0) { el[n * 2 + wave] = sl; er[n * 2 + wave] = sr; }
}

// ---------------- per-node softmax stats (no atomics, no -inf stored) ----------------
__global__ __launch_bounds__(64) void stats_k(const int* __restrict__ indptr,
                                              const int* __restrict__ eidx,
                                              const int* __restrict__ src,
                                              const float* __restrict__ el,
                                              const float* __restrict__ er,
                                              float* __restrict__ emax,
                                              float* __restrict__ denom) {
  int n = blockIdx.x, lane = threadIdx.x;
  int beg = indptr[n], end = indptr[n + 1];
  int h = lane & 1, slot = lane >> 1;
  float ern = er[n * 2 + h];
  float m = -3.4e38f;
  for (int i = beg + slot; i < end; i += 32) {
    int s = src[eidx[i]];
    m = fmaxf(m, lrelu(el[s * 2 + h] + ern));
  }
#pragma unroll
  for (int off = 2; off < 64; off <<= 1) m = fmaxf(m, __shfl_xor(m, off));
  float sum = 0.f;
  for (int i = beg + slot; i < end; i += 32) {
    int s = src[eidx[i]];
    sum += __expf(lrelu(el[s * 2 + h] + ern) - m);
  }
#pragma unroll
  for (int off = 2; off < 64; off <<= 1) sum += __shfl_xor(sum, off);
  if (lane < 2) {
    emax[n * 2 + lane] = (end > beg) ? m : 0.f;
    denom[n * 2 + lane] = sum;
  }
}

// ---------------- CSR gather-aggregate for one group of 2 heads ----------------
__global__ __launch_bounds__(128) void agg_k(const unsigned short* __restrict__ feat,
                                             const float* __restrict__ el,
                                             const float* __restrict__ er,
                                             const float* __restrict__ emax,
                                             const float* __restrict__ denom,
                                             const int* __restrict__ indptr,
                                             const int* __restrict__ eidx,
                                             const int* __restrict__ src,
                                             const unsigned short* __restrict__ bias,
                                             void* __restrict__ outv,
                                             float* __restrict__ hacc,
                                             unsigned short* __restrict__ hout,
                                             int F, int GF, int mode, int g, int HFtot,
                                             const int* __restrict__ flag) {
  __shared__ float we[2], mxs[2], erns[2];
  __shared__ float sred[1024];
  int n = blockIdx.x, tid = threadIdx.x, nth = blockDim.x;
  if (tid < 2) {
    mxs[tid] = emax[n * 2 + tid];
    erns[tid] = er[n * 2 + tid];
  }
  int head = (tid * 8) / F;
  float racc[8];
#pragma unroll
  for (int q = 0; q < 8; q++) racc[q] = 0.f;
  __syncthreads();
  int beg = indptr[n], end = indptr[n + 1];
  for (int i = beg; i < end; i++) {
    int s = src[eidx[i]];
    if (tid < 2) {
      float v = lrelu(el[s * 2 + tid] + erns[tid]);
      we[tid] = __expf(v - mxs[tid]);
    }
    __syncthreads();
    U16B u; u.v = *(const uint4*)(feat + (size_t)s * GF + tid * 8);
    float w = we[head];
#pragma unroll
    for (int q = 0; q < 8; q++) racc[q] += w * b2f(u.s[q]);
    __syncthreads();
  }
  float dn = denom[n * 2 + head];
  float inv = dn > 0.f ? 1.f / dn : 0.f;
  if (mode == 1) {
    float vals[8];
#pragma unroll
    for (int q = 0; q < 8; q++) vals[q] = racc[q] * inv + b2f(bias[tid * 8 + q]);
    size_t base = (size_t)n * HFtot + (size_t)g * GF + tid * 8;
    if (*flag) {
      float* of = (float*)outv;
      *(float4*)(of + base)     = make_float4(vals[0], vals[1], vals[2], vals[3]);
      *(float4*)(of + base + 4) = make_float4(vals[4], vals[5], vals[6], vals[7]);
    } else {
      U16B u;
#pragma unroll
      for (int q = 0; q < 8; q++) u.s[q] = f2b(vals[q]);
      *(uint4*)((unsigned short*)outv + base) = u.v;
    }
  } else {
#pragma unroll
    for (int q = 0; q < 8; q++)
      sred[tid * 8 + q] = gelu_f(racc[q] * inv + b2f(bias[tid * 8 + q]));
    __syncthreads();
    for (int f = tid; f < F; f += nth) {
      float s2 = sred[f] + sred[F + f];
      size_t idx = (size_t)n * F + f;
      if (g == 3)      hout[idx] = f2b((hacc[idx] + s2) * 0.125f);
      else if (g == 0) hacc[idx] = s2;
      else             hacc[idx] += s2;
    }
  }
}

extern "C" void kernel_launch(void* const* d_in, const int* in_sizes, int n_in,
                              void* d_out, int out_size, void* d_ws, size_t ws_size,
                              hipStream_t stream) {
  const int* src = (const int*)d_in[1];
  const int* dst = (const int*)d_in[2];

  char* ws = (char*)d_ws;
  size_t off = 0;
  auto carve = [&](size_t bytes) -> void* {
    void* p = ws + off;
    off += (bytes + 255) & ~(size_t)255;
    return p;
  };
  unsigned short* feat = (unsigned short*)carve((size_t)NN * 1024 * 2);  // 41 MB
  float* hacc = (float*)carve((size_t)NN * 256 * 4);                     // 20.5 MB
  unsigned short* hbuf = (unsigned short*)carve((size_t)NN * 256 * 2);   // 10.2 MB
  unsigned short* nodeb = (unsigned short*)carve((size_t)NN * 512 * 2);  // 20.5 MB
  unsigned short* W1b = (unsigned short*)carve((size_t)512 * 2048 * 2);
  unsigned short* W2b = (unsigned short*)carve((size_t)256 * 2048 * 2);
  unsigned short* W3b = (unsigned short*)carve((size_t)256 * 4096 * 2);
  unsigned short* al1b = (unsigned short*)carve(2048 * 2);
  unsigned short* ar1b = (unsigned short*)carve(2048 * 2);
  unsigned short* b1b  = (unsigned short*)carve(2048 * 2);
  unsigned short* al2b = (unsigned short*)carve(2048 * 2);
  unsigned short* ar2b = (unsigned short*)carve(2048 * 2);
  unsigned short* b2b  = (unsigned short*)carve(2048 * 2);
  unsigned short* al3b = (unsigned short*)carve(4096 * 2);
  unsigned short* ar3b = (unsigned short*)carve(4096 * 2);
  unsigned short* b3b  = (unsigned short*)carve(4096 * 2);
  float* el = (float*)carve((size_t)NN * 2 * 4);
  float* er = (float*)carve((size_t)NN * 2 * 4);
  float* emax = (float*)carve((size_t)NN * 2 * 4);
  float* denom = (float*)carve((size_t)NN * 2 * 4);
  int* deg = (int*)carve((size_t)NN * 4);
  int* indptr = (int*)carve((size_t)(NN + 1) * 4);
  int* cursor = (int*)carve((size_t)NN * 4);
  int* eidx = (int*)carve((size_t)NE * 4);
  int* flag = (int*)carve(256);

  // dtype detect + normalize all non-int inputs to bf16 copies
  detect_k<<<1, 256, 0, stream>>>((const unsigned short*)d_in[3], flag);
  auto conv = [&](const void* s, unsigned short* d, int n) {
    conv_k<<<(n + 255) / 256, 256, 0, stream>>>(s, d, n, flag);
  };
  conv(d_in[0], nodeb, NN * 512);
  conv(d_in[3], W1b, 512 * 2048);
  conv(d_in[4], al1b, 2048);  conv(d_in[5], ar1b, 2048);  conv(d_in[6], b1b, 2048);
  conv(d_in[7], W2b, 256 * 2048);
  conv(d_in[8], al2b, 2048);  conv(d_in[9], ar2b, 2048);  conv(d_in[10], b2b, 2048);
  conv(d_in[11], W3b, 256 * 4096);
  conv(d_in[12], al3b, 4096); conv(d_in[13], ar3b, 4096); conv(d_in[14], b3b, 4096);

  // CSR by dst
  hipMemsetAsync(deg, 0, (size_t)NN * 4, stream);
  hist_k<<<(NE + 255) / 256, 256, 0, stream>>>(dst, deg);
  scan_k<<<1, 1024, 0, stream>>>(deg, indptr, cursor);
  scatter_k<<<(NE + 255) / 256, 256, 0, stream>>>(dst, cursor, eidx);

  auto layer = [&](const unsigned short* A, int K, int F, const unsigned short* W,
                   const unsigned short* al, const unsigned short* ar,
                   const unsigned short* bb, int mode) {
    int GF = 2 * F;
    int HFtot = 8 * F;
    for (int g = 0; g < 4; g++) {
      dim3 gg((NN + 63) / 64, GF / 64);
      gemm_k<<<gg, 256, 0, stream>>>(A, W + (size_t)g * GF, feat, NN, K, HFtot, GF);
      elr_k<<<NN, 128, 0, stream>>>(feat, al + (size_t)g * GF, ar + (size_t)g * GF, el, er, F, GF);
      stats_k<<<NN, 64, 0, stream>>>(indptr, eidx, src, el, er, emax, denom);
      agg_k<<<NN, GF / 8, 0, stream>>>(feat, el, er, emax, denom, indptr, eidx, src,
                                       bb + (size_t)g * GF, d_out, hacc, hbuf,
                                       F, GF, mode, g, HFtot, flag);
    }
  };

  layer(nodeb, 512, 256, W1b, al1b, ar1b, b1b, 0);
  layer(hbuf, 256, 256, W2b, al2b, ar2b, b2b, 0);
  layer(hbuf, 256, 512, W3b, al3b, ar3b, b3b, 1);
}